// Round 19
// baseline (145.348 us; speedup 1.0000x reference)
//
#include <hip/hip_runtime.h>
#include <hip/hip_bf16.h>

typedef __bf16 bf16x8 __attribute__((ext_vector_type(8)));
typedef float  f32x4  __attribute__((ext_vector_type(4)));
typedef unsigned short u16;

__device__ __forceinline__ u16 f2bf(float f) {
    __bf16 h = (__bf16)f;
    return __builtin_bit_cast(u16, h);
}

__device__ __forceinline__ f32x4 mfma16(bf16x8 a, bf16x8 b, f32x4 c) {
    return __builtin_amdgcn_mfma_f32_16x16x32_bf16(a, b, c, 0, 0, 0);
}

__device__ __forceinline__ bf16x8 cvt8(float4 a0, float4 a1) {
    bf16x8 u;
    u[0] = (__bf16)a0.x; u[1] = (__bf16)a0.y; u[2] = (__bf16)a0.z; u[3] = (__bf16)a0.w;
    u[4] = (__bf16)a1.x; u[5] = (__bf16)a1.y; u[6] = (__bf16)a1.z; u[7] = (__bf16)a1.w;
    return u;
}

// async global->LDS, 16B per lane. LDS dest = wave-uniform base + lane*16.
__device__ __forceinline__ void gload16(const u16* g, u16* l) {
    __builtin_amdgcn_global_load_lds(
        (const __attribute__((address_space(1))) void*)g,
        (__attribute__((address_space(3))) void*)l, 16, 0, 0);
}

// ---------------------------------------------------------------------------
// cvt7: q,k,v (4M each) + Wq,Wk,Wv,Wo (1M each) fp32 -> bf16 concatenated.
// ---------------------------------------------------------------------------
__global__ __launch_bounds__(256) void cvt7(const float* __restrict__ q,
                                            const float* __restrict__ k,
                                            const float* __restrict__ v,
                                            const float* __restrict__ Wq,
                                            const float* __restrict__ Wk,
                                            const float* __restrict__ Wv,
                                            const float* __restrict__ Wo,
                                            u16* __restrict__ dst) {
    const int t = blockIdx.x * 256 + threadIdx.x;   // 0..2M-1
    const float* s;
    int o;
    if (t < 0x80000)       { s = q; o = t; }
    else if (t < 0x100000) { s = k; o = t - 0x80000; }
    else if (t < 0x180000) { s = v; o = t - 0x100000; }
    else {
        const int r = t - 0x180000;
        const int w = r >> 17;
        o = r & 0x1FFFF;
        s = (w == 0) ? Wq : (w == 1) ? Wk : (w == 2) ? Wv : Wo;
    }
    const int off = o * 8;
    float4 f0 = *(const float4*)(s + off);
    float4 f1 = *(const float4*)(s + off + 4);
    *(bf16x8*)(dst + (size_t)t * 8) = cvt8(f0, f1);
}

// ---------------------------------------------------------------------------
// Merged Q/K/V GEMM — 256x256 tile, BK=32, counted-vmcnt ring schedule.
// 512 thr / 8 waves (2Mx4N, wave-tile 128x64). LDS: 4-slot ring per operand
// (slot = 16KB = 256 rows x 32 cols bf16), tile j lives in slot j&3.
// 32 K-tiles x 2 phases. Per phase: 8 ds_read_b128 (quadrant qm=ph) ->
// issue 2 gload16 (half h=ph of tile j+3 into slot (j+3)&3, freed by tile
// j-1) -> s_barrier -> setprio+16 MFMA -> [tile end: vmcnt(8), tail 4/0]
// -> s_barrier. NO __syncthreads in-loop (avoids the vmcnt(0) drain).
// LDS layout (2-way max): paired rows, LDS-row lr=r>>1 is 128B of 8 16B
// slots; slot s=(r&1)*4+k4 stored at s^(lr&7). Stage chunk c: lr=c>>3,
// s=(c&7)^(lr&7), r=2lr+(s>>2), col16=s&3 -> linear dest c*16B.
// ---------------------------------------------------------------------------
__global__ __launch_bounds__(512, 2) void gemm_qkv(const u16* __restrict__ qb,
                                                   const u16* __restrict__ kb,
                                                   const u16* __restrict__ vb,
                                                   const u16* __restrict__ Wb,
                                                   u16* __restrict__ Qp,
                                                   u16* __restrict__ Kp,
                                                   u16* __restrict__ Vt) {
    constexpr int K = 1024, N = 1024;
    __shared__ __align__(16) u16 As[4][8192];   // 4 x 16 KB
    __shared__ __align__(16) u16 Bs[4][8192];   // 4 x 16 KB

    const int tid  = threadIdx.x;
    const int lane = tid & 63;
    const int w    = tid >> 6;          // 0..7
    const int wr = w >> 2, wc = w & 3;  // wave-tile: rows wr*128, cols wc*64
    const int wg    = (blockIdx.x & 7) * 24 + (blockIdx.x >> 3);  // XCD swizzle
    const int which = wg >> 6;          // 0..2
    const int inner = wg & 63;
    const int m0 = (inner >> 2) * 256, n0 = (inner & 3) * 256;
    const int colg = lane & 15, rowg = lane >> 4;

    const u16* A = (which == 0) ? qb : (which == 1) ? kb : vb;
    const u16* W = Wb + ((size_t)which << 20);
    const u16* Ab = A + (size_t)m0 * K;
    const u16* Bb = W + (size_t)n0 * K;

    // staging maps: per phase h in {0,1}: chunk c = h*512 + tid
    size_t srcOff[2];
    int dstIdx[2];
#pragma unroll
    for (int h = 0; h < 2; ++h) {
        const int c  = h * 512 + tid;
        const int lr = c >> 3;
        const int s  = (c & 7) ^ (lr & 7);
        const int r  = 2 * lr + (s >> 2);
        srcOff[h] = (size_t)r * K + (s & 3) * 8;   // u16 elems
        dstIdx[h] = c * 8;                         // u16 index
    }

    // fragment read offsets (u16 index within a slot)
    int ardA[2][4], ardB[4];
#pragma unroll
    for (int ph = 0; ph < 2; ++ph)
#pragma unroll
        for (int mi = 0; mi < 4; ++mi) {
            const int r  = wr * 128 + ph * 64 + mi * 16 + colg;
            const int lr = r >> 1;
            const int s  = (r & 1) * 4 + rowg;
            ardA[ph][mi] = lr * 64 + (s ^ (lr & 7)) * 8;
        }
#pragma unroll
    for (int ni = 0; ni < 4; ++ni) {
        const int r  = wc * 64 + ni * 16 + colg;
        const int lr = r >> 1;
        const int s  = (r & 1) * 4 + rowg;
        ardB[ni] = lr * 64 + (s ^ (lr & 7)) * 8;
    }

    f32x4 acc[8][4];
#pragma unroll
    for (int i = 0; i < 8; ++i)
#pragma unroll
        for (int j = 0; j < 4; ++j) acc[i][j] = (f32x4){0.f, 0.f, 0.f, 0.f};

    // prologue: stage tiles 0,1,2 into slots 0,1,2 (12 gloads/thread)
#pragma unroll
    for (int tt = 0; tt < 3; ++tt)
#pragma unroll
        for (int h = 0; h < 2; ++h) {
            gload16(Ab + srcOff[h] + tt * 32, &As[tt][dstIdx[h]]);
            gload16(Bb + srcOff[h] + tt * 32, &Bs[tt][dstIdx[h]]);
        }
    asm volatile("s_waitcnt vmcnt(8)" ::: "memory");   // tile 0 landed
    __builtin_amdgcn_s_barrier();

    for (int j = 0; j < 32; ++j) {
        const int sj = j & 3;
        const int st = (j + 3) & 3;
        const bool doStage = (j < 29);
#pragma unroll
        for (int ph = 0; ph < 2; ++ph) {
            bf16x8 af[4], bfr[4];
#pragma unroll
            for (int mi = 0; mi < 4; ++mi)
                af[mi] = *(const bf16x8*)(&As[sj][ardA[ph][mi]]);
#pragma unroll
            for (int ni = 0; ni < 4; ++ni)
                bfr[ni] = *(const bf16x8*)(&Bs[sj][ardB[ni]]);
            if (doStage) {
                gload16(Ab + srcOff[ph] + (j + 3) * 32, &As[st][dstIdx[ph]]);
                gload16(Bb + srcOff[ph] + (j + 3) * 32, &Bs[st][dstIdx[ph]]);
            }
            __builtin_amdgcn_s_barrier();
            __builtin_amdgcn_s_setprio(1);
#pragma unroll
            for (int mi = 0; mi < 4; ++mi)
#pragma unroll
                for (int ni = 0; ni < 4; ++ni)
                    acc[ph * 4 + mi][ni] = mfma16(af[mi], bfr[ni], acc[ph * 4 + mi][ni]);
            __builtin_amdgcn_s_setprio(0);
            if (ph == 1) {
                if (j <= 28)      asm volatile("s_waitcnt vmcnt(8)" ::: "memory");
                else if (j == 29) asm volatile("s_waitcnt vmcnt(4)" ::: "memory");
                else if (j == 30) asm volatile("s_waitcnt vmcnt(0)" ::: "memory");
            }
            __builtin_amdgcn_s_barrier();
        }
    }

    u16* Crm = (which == 0) ? Qp : Kp;
#pragma unroll
    for (int mi = 0; mi < 8; ++mi) {
#pragma unroll
        for (int ni = 0; ni < 4; ++ni) {
#pragma unroll
            for (int r = 0; r < 4; ++r) {
                const int row = m0 + wr * 128 + mi * 16 + rowg * 4 + r;
                const int col = n0 + wc * 64 + ni * 16 + colg;
                const float vv = acc[mi][ni][r];
                if (which < 2) {
                    Crm[(size_t)row * N + col] = f2bf(vv);
                } else {
                    const int b = row >> 11, tt = row & 2047;
                    const int h = col >> 6,  d = col & 63;
                    Vt[((size_t)((b * 16 + h) * 64 + d) << 11) + tt] = f2bf(vv);
                }
            }
        }
    }
}

// ---------------------------------------------------------------------------
// Output GEMM — r12 version (64x128 tile, 512 blocks, bf16 reg-staged,
// swizzled LDS, 2-phase dbuf pipeline). fp32 out.
// ---------------------------------------------------------------------------
__global__ __launch_bounds__(256) void gemm_out(const u16* __restrict__ Ap,
                                                const u16* __restrict__ W,
                                                float* __restrict__ Cp) {
    constexpr int K = 1024, N = 1024;
    __shared__ __align__(16) u16 As[2][2048];    // 2 x 4 KB
    __shared__ __align__(16) u16 Bs[2][4096];    // 2 x 8 KB

    const int tid  = threadIdx.x;
    const int lane = tid & 63;
    const int w    = tid >> 6;
    const int wr = w >> 1, wc = w & 1;
    const int wg = (blockIdx.x & 7) * 64 + (blockIdx.x >> 3);  // XCD swizzle
    const int m0 = (wg >> 3) * 64, n0 = (wg & 7) * 128;
    const int colg = lane & 15, rowg = lane >> 4;

    const int rowA = tid >> 2, kcA = tid & 3;
    const size_t aoff = (size_t)(m0 + rowA) * K + kcA * 8;
    const int wiA = rowA * 32 + (kcA ^ ((rowA >> 1) & 3)) * 8;

    size_t boff[2];
    int wiB[2];
#pragma unroll
    for (int i = 0; i < 2; ++i) {
        const int c   = i * 256 + tid;
        const int row = c >> 2;
        const int kc  = c & 3;
        boff[i] = (size_t)(n0 + row) * K + kc * 8;
        wiB[i] = row * 32 + (kc ^ ((row >> 1) & 3)) * 8;
    }
    const int kcr   = rowg ^ ((colg >> 1) & 3);
    const int rbase = colg * 32 + kcr * 8;

    f32x4 acc[2][4];
#pragma unroll
    for (int i = 0; i < 2; ++i)
#pragma unroll
        for (int j = 0; j < 4; ++j) acc[i][j] = (f32x4){0.f, 0.f, 0.f, 0.f};

    // prologue
    uint4 av = *(const uint4*)(Ap + aoff);
    uint4 bv[2];
#pragma unroll
    for (int i = 0; i < 2; ++i) bv[i] = *(const uint4*)(W + boff[i]);
    *(uint4*)(&As[0][wiA]) = av;
#pragma unroll
    for (int i = 0; i < 2; ++i) *(uint4*)(&Bs[0][wiB[i]]) = bv[i];
    __syncthreads();

    int p = 0;
    for (int t = 0; t < 32; ++t) {
        if (t < 31) {
            const int kk = (t + 1) * 32;
            av = *(const uint4*)(Ap + aoff + kk);
#pragma unroll
            for (int i = 0; i < 2; ++i) bv[i] = *(const uint4*)(W + boff[i] + kk);
        }
        {
            bf16x8 af[2], bfr[4];
#pragma unroll
            for (int mi = 0; mi < 2; ++mi)
                af[mi] = *(const bf16x8*)(&As[p][(wr * 32 + mi * 16) * 32 + rbase]);
#pragma unroll
            for (int ni = 0; ni < 4; ++ni)
                bfr[ni] = *(const bf16x8*)(&Bs[p][(wc * 64 + ni * 16) * 32 + rbase]);
#pragma unroll
            for (int mi = 0; mi < 2; ++mi)
#pragma unroll
                for (int ni = 0; ni < 4; ++ni)
                    acc[mi][ni] = mfma16(af[mi], bfr[ni], acc[mi][ni]);
        }
        if (t < 31) {
            *(uint4*)(&As[p ^ 1][wiA]) = av;
#pragma unroll
            for (int i = 0; i < 2; ++i) *(uint4*)(&Bs[p ^ 1][wiB[i]]) = bv[i];
        }
        __syncthreads();
        p ^= 1;
    }

#pragma unroll
    for (int mi = 0; mi < 2; ++mi)
#pragma unroll
        for (int ni = 0; ni < 4; ++ni)
#pragma unroll
            for (int r = 0; r < 4; ++r) {
                const int row = m0 + wr * 32 + mi * 16 + rowg * 4 + r;
                const int col = n0 + wc * 64 + ni * 16 + colg;
                Cp[(size_t)row * N + col] = acc[mi][ni][r];
            }
}

// ---------------------------------------------------------------------------
// Flash attention v3 (unchanged): 4-wave blocks, block-staged K/V in swizzled
// LDS, swapped QK^T (lane-local softmax), defer-rescale.
// ---------------------------------------------------------------------------
constexpr float CEXP = 0.18033688011112042f;  // 0.125 * log2(e)

__global__ __launch_bounds__(256) void attn_causal(const u16* __restrict__ Qp,
                                                   const u16* __restrict__ Kp,
                                                   const u16* __restrict__ Vt,
                                                   u16* __restrict__ concat) {
    constexpr int T = 2048, C = 1024;
    __shared__ __align__(16) u16 Ks[128 * 64];
    __shared__ __align__(16) u16 Vs[64 * 128];
    __shared__ __align__(16) u16 Pl[4][2048];

    const int tid  = threadIdx.x;
    const int lane = tid & 63;
    const int w    = tid >> 6;
    const int colg = lane & 15, rowg = lane >> 4;

    const int idx = blockIdx.x;
    const int xcd = idx & 7;
    const int i1  = idx >> 3;
    const int bh  = xcd * 4 + (i1 & 3);
    const int qg  = 31 - (i1 >> 2);
    const int b = bh >> 4, h = bh & 15;

    const int q0 = (qg * 4 + w) * 16;
    const int nt    = (q0 + 143) >> 7;
    const int ktmax = ((qg * 4 + 3) * 16 + 143) >> 7;

    const char* Kg = (const char*)(Kp + (size_t)(b * T) * C + h * 64);
    const char* Vg = (const char*)(Vt + ((size_t)(b * 16 + h) * 64) * T);
    char* Ksb = (char*)Ks;
    char* Vsb = (char*)Vs;
    char* Pw  = (char*)&Pl[w][0];

    const u16* Qb = Qp + (size_t)(b * T + q0 + colg) * C + h * 64;
    const bf16x8 qf0 = *(const bf16x8*)(Qb + rowg * 8);
    const bf16x8 qf1 = *(const bf16x8*)(Qb + 32 + rowg * 8);

    float mm = -1e30f, ll = 0.f;
    f32x4 O[4];
#pragma unroll
    for (int g = 0; g < 4; ++g) O[g] = (f32x4){0.f, 0.f, 0.f, 0.f};

    const int sw = (colg & 7) << 4;

    for (int kt = 0; kt < ktmax; ++kt) {
        const int kvb = kt * 128;
        uint4 kst[4], vst[4];
#pragma unroll
        for (int i2 = 0; i2 < 4; ++i2) {
            const int s  = i2 * 4096 + tid * 16;
            const int kv = s >> 7, ir = s & 127;
            kst[i2] = *(const uint4*)(Kg + (size_t)(kvb + kv) * 2048 + ir);
            const int d = s >> 8, irv = s & 255;
            vst[i2] = *(const uint4*)(Vg + (size_t)d * 4096 + (size_t)kvb * 2 + irv);
        }
#pragma unroll
        for (int i2 = 0; i2 < 4; ++i2) {
            const int s  = i2 * 4096 + tid * 16;
            const int kv = s >> 7;
            *(uint4*)(Ksb + (s ^ ((kv & 7) << 4))) = kst[i2];
            const int d = s >> 8;
            *(uint4*)(Vsb + (s ^ ((d & 7) << 4))) = vst[i2];
        }
        __syncthreads();

        if (kt < nt) {
            float pr[8][4];
#pragma unroll
            for (int sub = 0; sub < 8; ++sub) {
                const int kb = (sub * 16 + colg) * 128 + rowg * 16;
                bf16x8 kf0 = *(const bf16x8*)(Ksb + (kb ^ sw));
                bf16x8 kf1 = *(const bf16x8*)(Ksb + ((kb + 64) ^ sw));
                f32x4 t = (f32x4){0.f, 0.f, 0.f, 0.f};
                t = mfma16(kf0, qf0, t);
                t = mfma16(kf1, qf1, t);
#pragma unroll
                for (int r = 0; r < 4; ++r) pr[sub][r] = t[r];
            }
            if (kvb + 127 > q0) {
#pragma unroll
                for (int sub = 0; sub < 8; ++sub)
#pragma unroll
                    for (int r = 0; r < 4; ++r)
                        if (kvb + sub * 16 + rowg * 4 + r > q0 + colg) pr[sub][r] = -1e30f;
            }
            float mx[8];
#pragma unroll
            for (int sub = 0; sub < 8; ++sub)
                mx[sub] = fmaxf(fmaxf(pr[sub][0], pr[sub][1]), fmaxf(pr[sub][2], pr[sub][3]));
            float pm = fmaxf(fmaxf(fmaxf(mx[0], mx[1]), fmaxf(mx[2], mx[3])),
                             fmaxf(fmaxf(mx[4], mx[5]), fmaxf(mx[6], mx[7])));
            pm = fmaxf(pm, __shfl_xor(pm, 16, 64));
            pm = fmaxf(pm, __shfl_xor(pm, 32, 64));
            if (__any(pm > mm + 40.f)) {
                const float mn = fmaxf(mm, pm);
                const float sc = __builtin_amdgcn_exp2f((mm - mn) * CEXP);
                mm = mn;
                ll *= sc;
#pragma unroll
                for (int r = 0; r < 4; ++r) {
                    const float scr = __shfl(sc, (lane & 48) + rowg * 4 + r, 64);
#pragma unroll
                    for (int g = 0; g < 4; ++g) O[g][r] *= scr;
                }
            }
            float rs = 0.f;
#pragma unroll
            for (int sub = 0; sub < 8; ++sub) {
                const float e0 = __builtin_amdgcn_exp2f((pr[sub][0] - mm) * CEXP);
                const float e1 = __builtin_amdgcn_exp2f((pr[sub][1] - mm) * CEXP);
                const float e2 = __builtin_amdgcn_exp2f((pr[sub][2] - mm) * CEXP);
                const float e3 = __builtin_amdgcn_exp2f((pr[sub][3] - mm) * CEXP);
                pr[sub][0] = e0; pr[sub][1] = e1; pr[sub][2] = e2; pr[sub][3] = e3;
                rs += (e0 + e1) + (e2 + e3);
            }
            rs += __shfl_xor(rs, 16, 64);
            rs += __shfl_xor(rs, 32, 64);
            ll += rs;
#pragma unroll
            for (int sub = 0; sub < 8; ++sub) {
                uint2 pk;
                pk.x = (unsigned)f2bf(pr[sub][0]) | ((unsigned)f2bf(pr[sub][1]) << 16);
                pk.y = (unsigned)f2bf(pr[sub][2]) | ((unsigned)f2bf(pr[sub][3]) << 16);
                const int wb = (colg * 256 + sub * 32 + rowg * 8) ^ sw;
                *(uint2*)(Pw + wb) = pk;
            }
            bf16x8 pf[4];
#pragma unroll
            for (int kc = 0; kc < 4; ++kc)
                pf[kc] = *(const bf16x8*)(Pw + ((colg * 256 + kc * 64 + rowg * 16) ^ sw));
#pragma unroll
            for (int g = 0; g < 4; ++g) {
                const int vb0 = (g * 16 + colg) * 256 + rowg * 16;
#pragma unroll
                for (int kc = 0; kc < 4; ++kc) {
                    bf16x8 vf = *(const bf16x8*)(Vsb + ((vb0 + kc * 64) ^ sw));
                    O[g] = mfma16(pf[kc], vf, O[g]);
                }
            }
        }
        __syncthreads();
    }

#pragma unroll
    for (int r = 0; r < 4; ++r) {
        const float lr = __shfl(ll, (lane & 48) + rowg * 4 + r, 64);
        const float rc = 1.f / lr;
        const size_t base = (size_t)(b * T + q0 + rowg * 4 + r) * C + h * 64;
#pragma unroll
        for (int g = 0; g < 4; ++g)
            concat[base + g * 16 + colg] = f2bf(O[g][r] * rc);
    }
}

// ---------------------------------------------------------------------------
extern "C" void kernel_launch(void* const* d_in, const int* in_sizes, int n_in,
                              void* d_out, int out_size, void* d_ws, size_t ws_size,
                              hipStream_t stream) {
    const float* q  = (const float*)d_in[0];
    const float* k  = (const float*)d_in[1];
    const float* v  = (const float*)d_in[2];
    const float* Wq = (const float*)d_in[3];
    const float* Wk = (const float*)d_in[4];
    const float* Wv = (const float*)d_in[5];
    const float* Wo = (const float*)d_in[6];
    float* out = (float*)d_out;

    constexpr size_t NELEM = (size_t)4096 * 1024;  // 4M
    constexpr size_t WSZ   = (size_t)1 << 20;      // 1M
    u16* QB  = (u16*)d_ws;          // bf16 q          4M
    u16* KB  = QB + NELEM;          // bf16 k          4M
    u16* VB  = KB + NELEM;          // bf16 v          4M
    u16* Wbf = VB + NELEM;          // bf16 weights    4M
    u16* Qp  = Wbf + 4 * WSZ;       // proj Q          4M
    u16* Kp  = Qp + NELEM;          // proj K          4M
    u16* Vt  = Kp + NELEM;          // proj V (transp) 4M
    u16* Cc  = Vt + NELEM;          // attn concat     4M

    cvt7<<<8192, 256, 0, stream>>>(q, k, v, Wq, Wk, Wv, Wo, QB);

    gemm_qkv<<<192, 512, 0, stream>>>(QB, KB, VB, Wbf, Qp, Kp, Vt);

    attn_causal<<<1024, 256, 0, stream>>>(Qp, Kp, Vt, Cc);

    gemm_out<<<512, 256, 0, stream>>>(Cc, Wbf + 3 * WSZ, out);
}

// Round 20
// 132.176 us; speedup vs baseline: 1.0997x; 1.0997x over previous
//
#include <hip/hip_runtime.h>
#include <hip/hip_bf16.h>

typedef __bf16 bf16x8 __attribute__((ext_vector_type(8)));
typedef float  f32x4  __attribute__((ext_vector_type(4)));
typedef unsigned short u16;

__device__ __forceinline__ u16 f2bf(float f) {
    __bf16 h = (__bf16)f;
    return __builtin_bit_cast(u16, h);
}

__device__ __forceinline__ f32x4 mfma16(bf16x8 a, bf16x8 b, f32x4 c) {
    return __builtin_amdgcn_mfma_f32_16x16x32_bf16(a, b, c, 0, 0, 0);
}

__device__ __forceinline__ bf16x8 cvt8(float4 a0, float4 a1) {
    bf16x8 u;
    u[0] = (__bf16)a0.x; u[1] = (__bf16)a0.y; u[2] = (__bf16)a0.z; u[3] = (__bf16)a0.w;
    u[4] = (__bf16)a1.x; u[5] = (__bf16)a1.y; u[6] = (__bf16)a1.z; u[7] = (__bf16)a1.w;
    return u;
}

// async global->LDS, 16B per lane. LDS dest = wave-uniform base + lane*16.
__device__ __forceinline__ void gload16(const u16* g, u16* l) {
    __builtin_amdgcn_global_load_lds(
        (const __attribute__((address_space(1))) void*)g,
        (__attribute__((address_space(3))) void*)l, 16, 0, 0);
}

// ---------------------------------------------------------------------------
// cvtW: Wq,Wk,Wv,Wo (1M elems each) fp32 -> bf16 concatenated.
// ---------------------------------------------------------------------------
__global__ __launch_bounds__(256) void cvtW(const float* __restrict__ W0,
                                            const float* __restrict__ W1,
                                            const float* __restrict__ W2,
                                            const float* __restrict__ W3,
                                            u16* __restrict__ dst) {
    const int t     = blockIdx.x * 256 + threadIdx.x;   // 0..512K-1
    const int which = t >> 17;
    const int off   = (t & 0x1FFFF) * 8;
    const float* s  = (which == 0) ? W0 : (which == 1) ? W1 : (which == 2) ? W2 : W3;
    float4 f0 = *(const float4*)(s + off);
    float4 f1 = *(const float4*)(s + off + 4);
    *(bf16x8*)(dst + ((size_t)which << 20) + off) = cvt8(f0, f1);
}

// ---------------------------------------------------------------------------
// Merged Q/K/V GEMM — r13 version (best measured total): BK=32, swizzled
// single-buffered LDS, quad-contiguous global loads, 2 barriers/step,
// 8 waves / 512 thr (wave-tile 64x32), 768 blocks.
// ---------------------------------------------------------------------------
__global__ __launch_bounds__(512, 6) void gemm_qkv(const float* __restrict__ q,
                                                   const float* __restrict__ k,
                                                   const float* __restrict__ v,
                                                   const u16* __restrict__ Wb,
                                                   u16* __restrict__ Qp,
                                                   u16* __restrict__ Kp,
                                                   u16* __restrict__ Vt) {
    constexpr int K = 1024, N = 1024;
    __shared__ __align__(16) u16 As[4096];   // 8 KB
    __shared__ __align__(16) u16 Bs[4096];   // 8 KB

    const int tid  = threadIdx.x;
    const int lane = tid & 63;
    const int w    = tid >> 6;          // 0..7
    const int wr = w >> 2, wc = w & 3;  // 2M x 4N wave grid
    const int wg    = (blockIdx.x & 7) * 96 + (blockIdx.x >> 3);  // XCD swizzle
    const int which = wg >> 8;
    const int inner = wg & 255;
    const int m0 = (inner >> 3) * 128, n0 = (inner & 7) * 128;
    const int colg = lane & 15, rowg = lane >> 4;

    const float* A = (which == 0) ? q : (which == 1) ? k : v;
    const u16*   W = Wb + ((size_t)which << 20);

    const int rowS = tid >> 2, kcS = tid & 3;
    const size_t aoff = (size_t)(m0 + rowS) * K + kcS * 8;   // floats
    const size_t boff = (size_t)(n0 + rowS) * K + kcS * 8;   // u16s
    const int wio = rowS * 32 + (kcS ^ ((rowS >> 1) & 3)) * 8;

    const int kcr   = rowg ^ ((colg >> 1) & 3);
    const int rbase = colg * 32 + kcr * 8;

    f32x4 acc[4][2];
#pragma unroll
    for (int i = 0; i < 4; ++i)
#pragma unroll
        for (int j = 0; j < 2; ++j) acc[i][j] = (f32x4){0.f, 0.f, 0.f, 0.f};

    for (int t = 0; t < 32; ++t) {
        const int kk = t * 32;
        float4 a0 = *(const float4*)(A + aoff + kk);
        float4 a1 = *(const float4*)(A + aoff + kk + 4);
        uint4  bv = *(const uint4*)(W + boff + kk);
        *(bf16x8*)(&As[wio]) = cvt8(a0, a1);
        *(uint4*)(&Bs[wio]) = bv;
        __syncthreads();

        bf16x8 af[4], bfr[2];
#pragma unroll
        for (int mi = 0; mi < 4; ++mi)
            af[mi] = *(const bf16x8*)(&As[(wr * 64 + mi * 16) * 32 + rbase]);
#pragma unroll
        for (int ni = 0; ni < 2; ++ni)
            bfr[ni] = *(const bf16x8*)(&Bs[(wc * 32 + ni * 16) * 32 + rbase]);
#pragma unroll
        for (int mi = 0; mi < 4; ++mi)
#pragma unroll
            for (int ni = 0; ni < 2; ++ni)
                acc[mi][ni] = mfma16(af[mi], bfr[ni], acc[mi][ni]);
        __syncthreads();
    }

    u16* Crm = (which == 0) ? Qp : Kp;
#pragma unroll
    for (int mi = 0; mi < 4; ++mi) {
#pragma unroll
        for (int ni = 0; ni < 2; ++ni) {
#pragma unroll
            for (int r = 0; r < 4; ++r) {
                const int row = m0 + wr * 64 + mi * 16 + rowg * 4 + r;
                const int col = n0 + wc * 32 + ni * 16 + colg;
                const float vv = acc[mi][ni][r];
                if (which < 2) {
                    Crm[(size_t)row * N + col] = f2bf(vv);
                } else {
                    const int b = row >> 11, tt = row & 2047;
                    const int h = col >> 6,  d = col & 63;
                    Vt[((size_t)((b * 16 + h) * 64 + d) << 11) + tt] = f2bf(vv);
                }
            }
        }
    }
}

// ---------------------------------------------------------------------------
// Output GEMM — r12 version (64x128 tile, 512 blocks, bf16 reg-staged,
// swizzled LDS, 2-phase dbuf pipeline). fp32 out.
// ---------------------------------------------------------------------------
__global__ __launch_bounds__(256) void gemm_out(const u16* __restrict__ Ap,
                                                const u16* __restrict__ W,
                                                float* __restrict__ Cp) {
    constexpr int K = 1024, N = 1024;
    __shared__ __align__(16) u16 As[2][2048];    // 2 x 4 KB
    __shared__ __align__(16) u16 Bs[2][4096];    // 2 x 8 KB

    const int tid  = threadIdx.x;
    const int lane = tid & 63;
    const int w    = tid >> 6;
    const int wr = w >> 1, wc = w & 1;
    const int wg = (blockIdx.x & 7) * 64 + (blockIdx.x >> 3);  // XCD swizzle
    const int m0 = (wg >> 3) * 64, n0 = (wg & 7) * 128;
    const int colg = lane & 15, rowg = lane >> 4;

    const int rowA = tid >> 2, kcA = tid & 3;
    const size_t aoff = (size_t)(m0 + rowA) * K + kcA * 8;
    const int wiA = rowA * 32 + (kcA ^ ((rowA >> 1) & 3)) * 8;

    size_t boff[2];
    int wiB[2];
#pragma unroll
    for (int i = 0; i < 2; ++i) {
        const int c   = i * 256 + tid;
        const int row = c >> 2;
        const int kc  = c & 3;
        boff[i] = (size_t)(n0 + row) * K + kc * 8;
        wiB[i] = row * 32 + (kc ^ ((row >> 1) & 3)) * 8;
    }
    const int kcr   = rowg ^ ((colg >> 1) & 3);
    const int rbase = colg * 32 + kcr * 8;

    f32x4 acc[2][4];
#pragma unroll
    for (int i = 0; i < 2; ++i)
#pragma unroll
        for (int j = 0; j < 4; ++j) acc[i][j] = (f32x4){0.f, 0.f, 0.f, 0.f};

    // prologue
    uint4 av = *(const uint4*)(Ap + aoff);
    uint4 bv[2];
#pragma unroll
    for (int i = 0; i < 2; ++i) bv[i] = *(const uint4*)(W + boff[i]);
    *(uint4*)(&As[0][wiA]) = av;
#pragma unroll
    for (int i = 0; i < 2; ++i) *(uint4*)(&Bs[0][wiB[i]]) = bv[i];
    __syncthreads();

    int p = 0;
    for (int t = 0; t < 32; ++t) {
        if (t < 31) {
            const int kk = (t + 1) * 32;
            av = *(const uint4*)(Ap + aoff + kk);
#pragma unroll
            for (int i = 0; i < 2; ++i) bv[i] = *(const uint4*)(W + boff[i] + kk);
        }
        {
            bf16x8 af[2], bfr[4];
#pragma unroll
            for (int mi = 0; mi < 2; ++mi)
                af[mi] = *(const bf16x8*)(&As[p][(wr * 32 + mi * 16) * 32 + rbase]);
#pragma unroll
            for (int ni = 0; ni < 4; ++ni)
                bfr[ni] = *(const bf16x8*)(&Bs[p][(wc * 64 + ni * 16) * 32 + rbase]);
#pragma unroll
            for (int mi = 0; mi < 2; ++mi)
#pragma unroll
                for (int ni = 0; ni < 4; ++ni)
                    acc[mi][ni] = mfma16(af[mi], bfr[ni], acc[mi][ni]);
        }
        if (t < 31) {
            *(uint4*)(&As[p ^ 1][wiA]) = av;
#pragma unroll
            for (int i = 0; i < 2; ++i) *(uint4*)(&Bs[p ^ 1][wiB[i]]) = bv[i];
        }
        __syncthreads();
        p ^= 1;
    }

#pragma unroll
    for (int mi = 0; mi < 2; ++mi)
#pragma unroll
        for (int ni = 0; ni < 4; ++ni)
#pragma unroll
            for (int r = 0; r < 4; ++r) {
                const int row = m0 + wr * 32 + mi * 16 + rowg * 4 + r;
                const int col = n0 + wc * 64 + ni * 16 + colg;
                Cp[(size_t)row * N + col] = acc[mi][ni][r];
            }
}

// ---------------------------------------------------------------------------
// Flash attention v4: double-buffered global_load_lds K/V staging with
// source-permuted addresses (rule #21: linear LDS dest + inverse-permuted
// source; read addressing byte-identical to the proven v3 swizzle), T14
// schedule: issue stage(t+1) -> compute(t) -> barrier (DMA flies under
// QK+softmax+PV). Swapped QK^T lane-local softmax + defer-rescale kept.
// LDS: K 2x16KB + V 2x16KB + P 16KB = 80KB -> 2 blocks/CU.
// ---------------------------------------------------------------------------
constexpr float CEXP = 0.18033688011112042f;  // 0.125 * log2(e)

__global__ __launch_bounds__(256) void attn_causal(const u16* __restrict__ Qp,
                                                   const u16* __restrict__ Kp,
                                                   const u16* __restrict__ Vt,
                                                   u16* __restrict__ concat) {
    constexpr int T = 2048, C = 1024;
    __shared__ __align__(16) u16 Ks[2][128 * 64];   // [kv][d] 128B rows
    __shared__ __align__(16) u16 Vs[2][64 * 128];   // [d][kv] 256B rows
    __shared__ __align__(16) u16 Pl[4][2048];       // per-wave P

    const int tid  = threadIdx.x;
    const int lane = tid & 63;
    const int w    = tid >> 6;
    const int colg = lane & 15, rowg = lane >> 4;

    const int idx = blockIdx.x;
    const int xcd = idx & 7;
    const int i1  = idx >> 3;
    const int bh  = xcd * 4 + (i1 & 3);
    const int qg  = 31 - (i1 >> 2);
    const int b = bh >> 4, h = bh & 15;

    const int q0 = (qg * 4 + w) * 16;
    const int nt    = (q0 + 143) >> 7;
    const int ktmax = ((qg * 4 + 3) * 16 + 143) >> 7;

    const u16* Kg = Kp + (size_t)(b * T) * C + h * 64;          // kv-row stride C
    const u16* Vg = Vt + ((size_t)(b * 16 + h) * 64) * T;       // d-row stride T

    // staging maps (source-permuted so linear LDS == swizzled content):
    // K chunk c: krow=c>>3, kslot=(c&7)^(krow&7); LDS(r,sl) <- global slot sl^(r&7)
    // V chunk c: d=c>>4,    vslot=(c&15)^(d&7)
    size_t koff[4], voff[4];
    int dofs[4];
#pragma unroll
    for (int i = 0; i < 4; ++i) {
        const int c = i * 256 + tid;
        const int krow = c >> 3;
        const int ksl  = (c & 7) ^ (krow & 7);
        koff[i] = (size_t)krow * C + ksl * 8;     // u16; + kvb*C per tile
        const int d   = c >> 4;
        const int vsl = (c & 15) ^ (d & 7);
        voff[i] = (size_t)d * T + vsl * 8;        // u16; + kvb per tile
        dofs[i] = c * 8;
    }

    char* Pw = (char*)&Pl[w][0];

    const u16* Qb = Qp + (size_t)(b * T + q0 + colg) * C + h * 64;
    const bf16x8 qf0 = *(const bf16x8*)(Qb + rowg * 8);
    const bf16x8 qf1 = *(const bf16x8*)(Qb + 32 + rowg * 8);

    float mm = -1e30f, ll = 0.f;
    f32x4 O[4];
#pragma unroll
    for (int g = 0; g < 4; ++g) O[g] = (f32x4){0.f, 0.f, 0.f, 0.f};

    const int sw = (colg & 7) << 4;

    // prologue: stage tile 0 into buf 0
#pragma unroll
    for (int i = 0; i < 4; ++i) {
        gload16(Kg + koff[i], &Ks[0][dofs[i]]);
        gload16(Vg + voff[i], &Vs[0][dofs[i]]);
    }
    __syncthreads();

    int buf = 0;
    for (int kt = 0; kt < ktmax; ++kt) {
        // T14: issue stage(t+1) first; it flies under compute(t)
        if (kt + 1 < ktmax) {
            const size_t kvbn = (size_t)(kt + 1) * 128;
#pragma unroll
            for (int i = 0; i < 4; ++i) {
                gload16(Kg + kvbn * C + koff[i], &Ks[buf ^ 1][dofs[i]]);
                gload16(Vg + kvbn + voff[i], &Vs[buf ^ 1][dofs[i]]);
            }
        }

        if (kt < nt) {
            const int kvb = kt * 128;
            const char* Ksb = (const char*)&Ks[buf][0];
            const char* Vsb = (const char*)&Vs[buf][0];
            float pr[8][4];
#pragma unroll
            for (int sub = 0; sub < 8; ++sub) {
                const int kb = (sub * 16 + colg) * 128 + rowg * 16;
                bf16x8 kf0 = *(const bf16x8*)(Ksb + (kb ^ sw));
                bf16x8 kf1 = *(const bf16x8*)(Ksb + ((kb + 64) ^ sw));
                f32x4 t = (f32x4){0.f, 0.f, 0.f, 0.f};
                t = mfma16(kf0, qf0, t);
                t = mfma16(kf1, qf1, t);
#pragma unroll
                for (int r = 0; r < 4; ++r) pr[sub][r] = t[r];
            }
            if (kvb + 127 > q0) {
#pragma unroll
                for (int sub = 0; sub < 8; ++sub)
#pragma unroll
                    for (int r = 0; r < 4; ++r)
                        if (kvb + sub * 16 + rowg * 4 + r > q0 + colg) pr[sub][r] = -1e30f;
            }
            float mx[8];
#pragma unroll
            for (int sub = 0; sub < 8; ++sub)
                mx[sub] = fmaxf(fmaxf(pr[sub][0], pr[sub][1]), fmaxf(pr[sub][2], pr[sub][3]));
            float pm = fmaxf(fmaxf(fmaxf(mx[0], mx[1]), fmaxf(mx[2], mx[3])),
                             fmaxf(fmaxf(mx[4], mx[5]), fmaxf(mx[6], mx[7])));
            pm = fmaxf(pm, __shfl_xor(pm, 16, 64));
            pm = fmaxf(pm, __shfl_xor(pm, 32, 64));
            if (__any(pm > mm + 40.f)) {
                const float mn = fmaxf(mm, pm);
                const float sc = __builtin_amdgcn_exp2f((mm - mn) * CEXP);
                mm = mn;
                ll *= sc;
#pragma unroll
                for (int r = 0; r < 4; ++r) {
                    const float scr = __shfl(sc, (lane & 48) + rowg * 4 + r, 64);
#pragma unroll
                    for (int g = 0; g < 4; ++g) O[g][r] *= scr;
                }
            }
            float rs = 0.f;
#pragma unroll
            for (int sub = 0; sub < 8; ++sub) {
                const float e0 = __builtin_amdgcn_exp2f((pr[sub][0] - mm) * CEXP);
                const float e1 = __builtin_amdgcn_exp2f((pr[sub][1] - mm) * CEXP);
                const float e2 = __builtin_amdgcn_exp2f((pr[sub][2] - mm) * CEXP);
                const float e3 = __builtin_amdgcn_exp2f((pr[sub][3] - mm) * CEXP);
                pr[sub][0] = e0; pr[sub][1] = e1; pr[sub][2] = e2; pr[sub][3] = e3;
                rs += (e0 + e1) + (e2 + e3);
            }
            rs += __shfl_xor(rs, 16, 64);
            rs += __shfl_xor(rs, 32, 64);
            ll += rs;
#pragma unroll
            for (int sub = 0; sub < 8; ++sub) {
                uint2 pk;
                pk.x = (unsigned)f2bf(pr[sub][0]) | ((unsigned)f2bf(pr[sub][1]) << 16);
                pk.y = (unsigned)f2bf(pr[sub][2]) | ((unsigned)f2bf(pr[sub][3]) << 16);
                const int wb = (colg * 256 + sub * 32 + rowg * 8) ^ sw;
                *(uint2*)(Pw + wb) = pk;
            }
            bf16x8 pf[4];
#pragma unroll
            for (int kc = 0; kc < 4; ++kc)
                pf[kc] = *(const bf16x8*)(Pw + ((colg * 256 + kc * 64 + rowg * 16) ^ sw));
#pragma unroll
            for (int g = 0; g < 4; ++g) {
                const int vb0 = (g * 16 + colg) * 256 + rowg * 16;
#pragma unroll
                for (int kc = 0; kc < 4; ++kc) {
                    bf16x8 vf = *(const bf16x8*)(Vsb + ((vb0 + kc * 64) ^ sw));
                    O[g] = mfma16(pf[kc], vf, O[g]);
                }
            }
        }
        __syncthreads();   // drains stage(t+1) DMA (covered by compute)
        buf ^= 1;
    }

#pragma unroll
    for (int r = 0; r < 4; ++r) {
        const float lr = __shfl(ll, (lane & 48) + rowg * 4 + r, 64);
        const float rc = 1.f / lr;
        const size_t base = (size_t)(b * T + q0 + rowg * 4 + r) * C + h * 64;
#pragma unroll
        for (int g = 0; g < 4; ++g)
            concat[base + g * 16 + colg] = f2bf(O[g][r] * rc);
    }
}

// ---------------------------------------------------------------------------
extern "C" void kernel_launch(void* const* d_in, const int* in_sizes, int n_in,
                              void* d_out, int out_size, void* d_ws, size_t ws_size,
                              hipStream_t stream) {
    const float* q  = (const float*)d_in[0];
    const float* k  = (const float*)d_in[1];
    const float* v  = (const float*)d_in[2];
    const float* Wq = (const float*)d_in[3];
    const float* Wk = (const float*)d_in[4];
    const float* Wv = (const float*)d_in[5];
    const float* Wo = (const float*)d_in[6];
    float* out = (float*)d_out;

    constexpr size_t NELEM = (size_t)4096 * 1024;  // 4M
    constexpr size_t WSZ   = (size_t)1 << 20;      // 1M
    u16* Wbf = (u16*)d_ws;          // bf16 weights    4M
    u16* Qp  = Wbf + 4 * WSZ;       // proj Q          4M
    u16* Kp  = Qp + NELEM;          // proj K          4M
    u16* Vt  = Kp + NELEM;          // proj V (transp) 4M
    u16* Cc  = Vt + NELEM;          // attn concat     4M

    cvtW<<<2048, 256, 0, stream>>>(Wq, Wk, Wv, Wo, Wbf);

    gemm_qkv<<<768, 512, 0, stream>>>(q, k, v, Wbf, Qp, Kp, Vt);

    attn_causal<<<1024, 256, 0, stream>>>(Qp, Kp, Vt, Cc);

    gemm_out<<<512, 256, 0, stream>>>(Cc, Wbf + 3 * WSZ, out);
}